// Round 1
// baseline (226.868 us; speedup 1.0000x reference)
//
#include <hip/hip_runtime.h>

// Problem collapses: output = classifier(node 0) only.
//   node0(block3) <- node1(block2) <- {0,2,4,6}(block1), all block1 nodes are
//   indeg * P1 where P1 = pool(lrelu(conv1(x)+b1)). Sum of indegs over
//   {0,2,4,6} = 1+3+3+5 = 12.  agg2 = conv2(12*P1) + 4*b2 (indeg2(1)=4).
//   agg3 = conv3(p2) + 1*b3 (indeg3(0)=1). Then pool, mean(8x8), dot wc + bc.

#define LRELU(v) fmaxf((v), 0.2f * (v))

// ---------------- Kernel 1: conv1(4->32, 64x64) + b1, lrelu, pool2, *12 ----
__global__ __launch_bounds__(256) void k1(const float* __restrict__ x,
                                          const float* __restrict__ w1,
                                          const float* __restrict__ b1,
                                          float* __restrict__ P1) {
    __shared__ float xs[4][34][34];
    const int bx = blockIdx.x;          // 16 = 4 tiles x 4 co-groups
    const int b  = blockIdx.y;          // 32
    const int tile = bx & 3, cog = bx >> 2;
    const int ty0 = (tile >> 1) * 16, tx0 = (tile & 1) * 16;  // pooled tile origin
    const int t = threadIdx.x;

    // stage 34x34 input region (zero halo, SAME padding) for 4 cin
    for (int idx = t; idx < 4 * 34 * 34; idx += 256) {
        int cin = idx / (34 * 34);
        int rem = idx % (34 * 34);
        int yy = rem / 34, xx = rem % 34;
        int gy = 2 * ty0 - 1 + yy, gx = 2 * tx0 - 1 + xx;
        float v = 0.f;
        if (gy >= 0 && gy < 64 && gx >= 0 && gx < 64)
            v = x[((b * 4 + cin) * 64 + gy) * 64 + gx];
        xs[cin][yy][xx] = v;
    }
    __syncthreads();

    const int py = t >> 4, px = t & 15;   // pooled coords inside tile (16x16)
    float r[4][4][4];
    #pragma unroll
    for (int c = 0; c < 4; ++c)
        #pragma unroll
        for (int yy = 0; yy < 4; ++yy)
            #pragma unroll
            for (int xx = 0; xx < 4; ++xx)
                r[c][yy][xx] = xs[c][2 * py + yy][2 * px + xx];

    #pragma unroll 1
    for (int co = 0; co < 8; ++co) {
        const int gco = cog * 8 + co;
        const float bias = b1[gco];
        float a00 = bias, a01 = bias, a10 = bias, a11 = bias;
        #pragma unroll
        for (int c = 0; c < 4; ++c) {
            #pragma unroll
            for (int i = 0; i < 3; ++i) {
                #pragma unroll
                for (int j = 0; j < 3; ++j) {
                    const float w = w1[(gco * 4 + c) * 9 + i * 3 + j]; // uniform -> s_load
                    a00 += w * r[c][i][j];
                    a01 += w * r[c][i][j + 1];
                    a10 += w * r[c][i + 1][j];
                    a11 += w * r[c][i + 1][j + 1];
                }
            }
        }
        const float m = fmaxf(fmaxf(LRELU(a00), LRELU(a01)),
                              fmaxf(LRELU(a10), LRELU(a11)));
        P1[((b * 32 + gco) * 32 + ty0 + py) * 32 + tx0 + px] = 12.f * m;
    }
}

// ---------------- Kernel 2: conv2(32->64, 32x32) + 4*b2, lrelu, pool2 ------
__global__ __launch_bounds__(256) void k2(const float* __restrict__ P1,
                                          const float* __restrict__ w2,
                                          const float* __restrict__ b2,
                                          float* __restrict__ p2) {
    __shared__ float xs[8][34][34];
    const int cog = blockIdx.x;   // 16 groups of 4 co
    const int b   = blockIdx.y;
    const int t   = threadIdx.x;
    const int py = t >> 4, px = t & 15;   // full 16x16 pooled plane

    float acc[4][2][2];
    #pragma unroll
    for (int co = 0; co < 4; ++co) {
        const float bias = 4.f * b2[cog * 4 + co];
        acc[co][0][0] = bias; acc[co][0][1] = bias;
        acc[co][1][0] = bias; acc[co][1][1] = bias;
    }

    for (int cc = 0; cc < 4; ++cc) {       // cin chunks of 8
        __syncthreads();
        for (int idx = t; idx < 8 * 34 * 34; idx += 256) {
            int cl = idx / (34 * 34);
            int rem = idx % (34 * 34);
            int yy = rem / 34, xx = rem % 34;
            int gy = yy - 1, gx = xx - 1;
            float v = 0.f;
            if (gy >= 0 && gy < 32 && gx >= 0 && gx < 32)
                v = P1[((b * 32 + cc * 8 + cl) * 32 + gy) * 32 + gx];
            xs[cl][yy][xx] = v;
        }
        __syncthreads();
        #pragma unroll 1
        for (int cl = 0; cl < 8; ++cl) {
            float r[4][4];
            #pragma unroll
            for (int yy = 0; yy < 4; ++yy)
                #pragma unroll
                for (int xx = 0; xx < 4; ++xx)
                    r[yy][xx] = xs[cl][2 * py + yy][2 * px + xx];
            const int cin = cc * 8 + cl;
            #pragma unroll
            for (int co = 0; co < 4; ++co) {
                #pragma unroll
                for (int i = 0; i < 3; ++i) {
                    #pragma unroll
                    for (int j = 0; j < 3; ++j) {
                        const float w = w2[((cog * 4 + co) * 32 + cin) * 9 + i * 3 + j];
                        acc[co][0][0] += w * r[i][j];
                        acc[co][0][1] += w * r[i][j + 1];
                        acc[co][1][0] += w * r[i + 1][j];
                        acc[co][1][1] += w * r[i + 1][j + 1];
                    }
                }
            }
        }
    }
    #pragma unroll
    for (int co = 0; co < 4; ++co) {
        const float m = fmaxf(fmaxf(LRELU(acc[co][0][0]), LRELU(acc[co][0][1])),
                              fmaxf(LRELU(acc[co][1][0]), LRELU(acc[co][1][1])));
        p2[((b * 64 + cog * 4 + co) * 16 + py) * 16 + px] = m;
    }
}

// -- Kernel 3: conv3(64->128, 16x16)+b3, lrelu, pool2, mean(8x8), dot wc+bc --
__global__ __launch_bounds__(256) void k3(const float* __restrict__ p2,
                                          const float* __restrict__ w3,
                                          const float* __restrict__ b3,
                                          const float* __restrict__ wc,
                                          const float* __restrict__ bc,
                                          float* __restrict__ out) {
    __shared__ float xs[16][18][18];
    const int cog = blockIdx.x;   // 16 groups of 8 co
    const int b   = blockIdx.y;
    const int t   = threadIdx.x;
    const int wv  = __builtin_amdgcn_readfirstlane(t >> 6);  // wave id, scalar
    const int s   = t & 63;
    const int py  = s >> 3, px = s & 7;   // 8x8 pooled plane

    float acc[2][2][2];
    #pragma unroll
    for (int k = 0; k < 2; ++k) {
        const float bias = b3[cog * 8 + wv + 4 * k];
        acc[k][0][0] = bias; acc[k][0][1] = bias;
        acc[k][1][0] = bias; acc[k][1][1] = bias;
    }

    for (int cc = 0; cc < 4; ++cc) {       // cin chunks of 16
        __syncthreads();
        for (int idx = t; idx < 16 * 18 * 18; idx += 256) {
            int cl = idx / (18 * 18);
            int rem = idx % (18 * 18);
            int yy = rem / 18, xx = rem % 18;
            int gy = yy - 1, gx = xx - 1;
            float v = 0.f;
            if (gy >= 0 && gy < 16 && gx >= 0 && gx < 16)
                v = p2[((b * 64 + cc * 16 + cl) * 16 + gy) * 16 + gx];
            xs[cl][yy][xx] = v;
        }
        __syncthreads();
        #pragma unroll 1
        for (int cl = 0; cl < 16; ++cl) {
            float r[4][4];
            #pragma unroll
            for (int yy = 0; yy < 4; ++yy)
                #pragma unroll
                for (int xx = 0; xx < 4; ++xx)
                    r[yy][xx] = xs[cl][2 * py + yy][2 * px + xx];
            const int cin = cc * 16 + cl;
            #pragma unroll
            for (int k = 0; k < 2; ++k) {
                const int gco = cog * 8 + wv + 4 * k;   // wave-uniform
                #pragma unroll
                for (int i = 0; i < 3; ++i) {
                    #pragma unroll
                    for (int j = 0; j < 3; ++j) {
                        const float w = w3[(gco * 64 + cin) * 9 + i * 3 + j];
                        acc[k][0][0] += w * r[i][j];
                        acc[k][0][1] += w * r[i][j + 1];
                        acc[k][1][0] += w * r[i + 1][j];
                        acc[k][1][1] += w * r[i + 1][j + 1];
                    }
                }
            }
        }
    }

    float part = 0.f;
    #pragma unroll
    for (int k = 0; k < 2; ++k) {
        float m = fmaxf(fmaxf(LRELU(acc[k][0][0]), LRELU(acc[k][0][1])),
                        fmaxf(LRELU(acc[k][1][0]), LRELU(acc[k][1][1])));
        // sum over the 64 lanes (= the 8x8 pooled plane)
        #pragma unroll
        for (int off = 32; off > 0; off >>= 1) m += __shfl_down(m, off);
        const int gco = cog * 8 + wv + 4 * k;
        part += m * (1.f / 64.f) * wc[gco];
    }
    if (s == 0) {
        if (cog == 0 && wv == 0) part += bc[0];
        atomicAdd(&out[b], part);
    }
}

extern "C" void kernel_launch(void* const* d_in, const int* in_sizes, int n_in,
                              void* d_out, int out_size, void* d_ws, size_t ws_size,
                              hipStream_t stream) {
    const float* x  = (const float*)d_in[0];
    const float* w1 = (const float*)d_in[1];
    const float* b1 = (const float*)d_in[2];
    const float* w2 = (const float*)d_in[3];
    const float* b2 = (const float*)d_in[4];
    const float* w3 = (const float*)d_in[5];
    const float* b3 = (const float*)d_in[6];
    const float* wc = (const float*)d_in[7];
    const float* bc = (const float*)d_in[8];
    float* out = (float*)d_out;

    float* P1 = (float*)d_ws;                    // [32,32,32,32] = 4 MB
    float* p2 = P1 + 32 * 32 * 32 * 32;          // [32,64,16,16] = 2 MB

    hipMemsetAsync(out, 0, 32 * sizeof(float), stream);   // out accumulated atomically
    k1<<<dim3(16, 32), 256, 0, stream>>>(x, w1, b1, P1);
    k2<<<dim3(16, 32), 256, 0, stream>>>(P1, w2, b2, p2);
    k3<<<dim3(16, 32), 256, 0, stream>>>(p2, w3, b3, wc, bc, out);
}

// Round 2
// 224.107 us; speedup vs baseline: 1.0123x; 1.0123x over previous
//
#include <hip/hip_runtime.h>

// Problem collapses: output = classifier(node 0) only.
//   node0(block3) <- node1(block2) <- {0,2,4,6}(block1), all block1 nodes are
//   indeg * P1 where P1 = pool(lrelu(conv1(x)+b1)). Sum of indegs over
//   {0,2,4,6} = 1+3+3+5 = 12.  agg2 = conv2(12*P1) + 4*b2 (indeg2(1)=4).
//   agg3 = conv3(p2) + 1*b3 (indeg3(0)=1). Then pool, mean(8x8), dot wc + bc.
//
// R2: ILP fixes. (1) fully unroll cin loops so the compiler software-
// pipelines ds_reads under FMAs (was #pragma unroll 1 -> serial load/compute,
// VALUBusy 26%). (2) float2 LDS reads (ds_read_b64): the stride-2 column
// pattern from pooling put scalar reads on even banks only (2x phase
// overhead); b64 pairs are bandwidth-optimal and halve issue count.

#define LRELU(v) fmaxf((v), 0.2f * (v))

// ---------------- Kernel 1: conv1(4->32, 64x64) + b1, lrelu, pool2, *12 ----
__global__ __launch_bounds__(256) void k1(const float* __restrict__ x,
                                          const float* __restrict__ w1,
                                          const float* __restrict__ b1,
                                          float* __restrict__ P1) {
    __shared__ float xs[4][34][34];
    const int bx = blockIdx.x;          // 16 = 4 tiles x 4 co-groups
    const int b  = blockIdx.y;          // 32
    const int tile = bx & 3, cog = bx >> 2;
    const int ty0 = (tile >> 1) * 16, tx0 = (tile & 1) * 16;  // pooled tile origin
    const int t = threadIdx.x;

    // stage 34x34 input region (zero halo, SAME padding) for 4 cin
    for (int idx = t; idx < 4 * 34 * 34; idx += 256) {
        int cin = idx / (34 * 34);
        int rem = idx % (34 * 34);
        int yy = rem / 34, xx = rem % 34;
        int gy = 2 * ty0 - 1 + yy, gx = 2 * tx0 - 1 + xx;
        float v = 0.f;
        if (gy >= 0 && gy < 64 && gx >= 0 && gx < 64)
            v = x[((b * 4 + cin) * 64 + gy) * 64 + gx];
        xs[cin][yy][xx] = v;
    }
    __syncthreads();

    const int py = t >> 4, px = t & 15;   // pooled coords inside tile (16x16)
    float r[4][4][4];
    #pragma unroll
    for (int c = 0; c < 4; ++c)
        #pragma unroll
        for (int yy = 0; yy < 4; ++yy) {
            const float2* p = (const float2*)&xs[c][2 * py + yy][2 * px];
            float2 lo = p[0], hi = p[1];
            r[c][yy][0] = lo.x; r[c][yy][1] = lo.y;
            r[c][yy][2] = hi.x; r[c][yy][3] = hi.y;
        }

    #pragma unroll 4
    for (int co = 0; co < 8; ++co) {
        const int gco = cog * 8 + co;
        const float bias = b1[gco];
        float a00 = bias, a01 = bias, a10 = bias, a11 = bias;
        #pragma unroll
        for (int c = 0; c < 4; ++c) {
            #pragma unroll
            for (int i = 0; i < 3; ++i) {
                #pragma unroll
                for (int j = 0; j < 3; ++j) {
                    const float w = w1[(gco * 4 + c) * 9 + i * 3 + j]; // uniform -> s_load
                    a00 += w * r[c][i][j];
                    a01 += w * r[c][i][j + 1];
                    a10 += w * r[c][i + 1][j];
                    a11 += w * r[c][i + 1][j + 1];
                }
            }
        }
        const float m = fmaxf(fmaxf(LRELU(a00), LRELU(a01)),
                              fmaxf(LRELU(a10), LRELU(a11)));
        P1[((b * 32 + gco) * 32 + ty0 + py) * 32 + tx0 + px] = 12.f * m;
    }
}

// ---------------- Kernel 2: conv2(32->64, 32x32) + 4*b2, lrelu, pool2 ------
__global__ __launch_bounds__(256) void k2(const float* __restrict__ P1,
                                          const float* __restrict__ w2,
                                          const float* __restrict__ b2,
                                          float* __restrict__ p2) {
    __shared__ float xs[8][34][34];
    const int cog = blockIdx.x;   // 16 groups of 4 co
    const int b   = blockIdx.y;
    const int t   = threadIdx.x;
    const int py = t >> 4, px = t & 15;   // full 16x16 pooled plane

    float acc[4][2][2];
    #pragma unroll
    for (int co = 0; co < 4; ++co) {
        const float bias = 4.f * b2[cog * 4 + co];
        acc[co][0][0] = bias; acc[co][0][1] = bias;
        acc[co][1][0] = bias; acc[co][1][1] = bias;
    }

    for (int cc = 0; cc < 4; ++cc) {       // cin chunks of 8
        __syncthreads();
        for (int idx = t; idx < 8 * 34 * 34; idx += 256) {
            int cl = idx / (34 * 34);
            int rem = idx % (34 * 34);
            int yy = rem / 34, xx = rem % 34;
            int gy = yy - 1, gx = xx - 1;
            float v = 0.f;
            if (gy >= 0 && gy < 32 && gx >= 0 && gx < 32)
                v = P1[((b * 32 + cc * 8 + cl) * 32 + gy) * 32 + gx];
            xs[cl][yy][xx] = v;
        }
        __syncthreads();
        #pragma unroll
        for (int cl = 0; cl < 8; ++cl) {
            float r[4][4];
            #pragma unroll
            for (int yy = 0; yy < 4; ++yy) {
                const float2* p = (const float2*)&xs[cl][2 * py + yy][2 * px];
                float2 lo = p[0], hi = p[1];
                r[yy][0] = lo.x; r[yy][1] = lo.y;
                r[yy][2] = hi.x; r[yy][3] = hi.y;
            }
            const int cin = cc * 8 + cl;
            #pragma unroll
            for (int co = 0; co < 4; ++co) {
                #pragma unroll
                for (int i = 0; i < 3; ++i) {
                    #pragma unroll
                    for (int j = 0; j < 3; ++j) {
                        const float w = w2[((cog * 4 + co) * 32 + cin) * 9 + i * 3 + j];
                        acc[co][0][0] += w * r[i][j];
                        acc[co][0][1] += w * r[i][j + 1];
                        acc[co][1][0] += w * r[i + 1][j];
                        acc[co][1][1] += w * r[i + 1][j + 1];
                    }
                }
            }
        }
    }
    #pragma unroll
    for (int co = 0; co < 4; ++co) {
        const float m = fmaxf(fmaxf(LRELU(acc[co][0][0]), LRELU(acc[co][0][1])),
                              fmaxf(LRELU(acc[co][1][0]), LRELU(acc[co][1][1])));
        p2[((b * 64 + cog * 4 + co) * 16 + py) * 16 + px] = m;
    }
}

// -- Kernel 3: conv3(64->128, 16x16)+b3, lrelu, pool2, mean(8x8), dot wc+bc --
__global__ __launch_bounds__(256) void k3(const float* __restrict__ p2,
                                          const float* __restrict__ w3,
                                          const float* __restrict__ b3,
                                          const float* __restrict__ wc,
                                          const float* __restrict__ bc,
                                          float* __restrict__ out) {
    __shared__ float xs[16][18][18];
    const int cog = blockIdx.x;   // 16 groups of 8 co
    const int b   = blockIdx.y;
    const int t   = threadIdx.x;
    const int wv  = __builtin_amdgcn_readfirstlane(t >> 6);  // wave id, scalar
    const int s   = t & 63;
    const int py  = s >> 3, px = s & 7;   // 8x8 pooled plane

    float acc[2][2][2];
    #pragma unroll
    for (int k = 0; k < 2; ++k) {
        const float bias = b3[cog * 8 + wv + 4 * k];
        acc[k][0][0] = bias; acc[k][0][1] = bias;
        acc[k][1][0] = bias; acc[k][1][1] = bias;
    }

    for (int cc = 0; cc < 4; ++cc) {       // cin chunks of 16
        __syncthreads();
        for (int idx = t; idx < 16 * 18 * 18; idx += 256) {
            int cl = idx / (18 * 18);
            int rem = idx % (18 * 18);
            int yy = rem / 18, xx = rem % 18;
            int gy = yy - 1, gx = xx - 1;
            float v = 0.f;
            if (gy >= 0 && gy < 16 && gx >= 0 && gx < 16)
                v = p2[((b * 64 + cc * 16 + cl) * 16 + gy) * 16 + gx];
            xs[cl][yy][xx] = v;
        }
        __syncthreads();
        #pragma unroll
        for (int cl = 0; cl < 16; ++cl) {
            float r[4][4];
            #pragma unroll
            for (int yy = 0; yy < 4; ++yy) {
                const float2* p = (const float2*)&xs[cl][2 * py + yy][2 * px];
                float2 lo = p[0], hi = p[1];
                r[yy][0] = lo.x; r[yy][1] = lo.y;
                r[yy][2] = hi.x; r[yy][3] = hi.y;
            }
            const int cin = cc * 16 + cl;
            #pragma unroll
            for (int k = 0; k < 2; ++k) {
                const int gco = cog * 8 + wv + 4 * k;   // wave-uniform
                #pragma unroll
                for (int i = 0; i < 3; ++i) {
                    #pragma unroll
                    for (int j = 0; j < 3; ++j) {
                        const float w = w3[(gco * 64 + cin) * 9 + i * 3 + j];
                        acc[k][0][0] += w * r[i][j];
                        acc[k][0][1] += w * r[i][j + 1];
                        acc[k][1][0] += w * r[i + 1][j];
                        acc[k][1][1] += w * r[i + 1][j + 1];
                    }
                }
            }
        }
    }

    float part = 0.f;
    #pragma unroll
    for (int k = 0; k < 2; ++k) {
        float m = fmaxf(fmaxf(LRELU(acc[k][0][0]), LRELU(acc[k][0][1])),
                        fmaxf(LRELU(acc[k][1][0]), LRELU(acc[k][1][1])));
        // sum over the 64 lanes (= the 8x8 pooled plane)
        #pragma unroll
        for (int off = 32; off > 0; off >>= 1) m += __shfl_down(m, off);
        const int gco = cog * 8 + wv + 4 * k;
        part += m * (1.f / 64.f) * wc[gco];
    }
    if (s == 0) {
        if (cog == 0 && wv == 0) part += bc[0];
        atomicAdd(&out[b], part);
    }
}

extern "C" void kernel_launch(void* const* d_in, const int* in_sizes, int n_in,
                              void* d_out, int out_size, void* d_ws, size_t ws_size,
                              hipStream_t stream) {
    const float* x  = (const float*)d_in[0];
    const float* w1 = (const float*)d_in[1];
    const float* b1 = (const float*)d_in[2];
    const float* w2 = (const float*)d_in[3];
    const float* b2 = (const float*)d_in[4];
    const float* w3 = (const float*)d_in[5];
    const float* b3 = (const float*)d_in[6];
    const float* wc = (const float*)d_in[7];
    const float* bc = (const float*)d_in[8];
    float* out = (float*)d_out;

    float* P1 = (float*)d_ws;                    // [32,32,32,32] = 4 MB
    float* p2 = P1 + 32 * 32 * 32 * 32;          // [32,64,16,16] = 2 MB

    hipMemsetAsync(out, 0, 32 * sizeof(float), stream);   // out accumulated atomically
    k1<<<dim3(16, 32), 256, 0, stream>>>(x, w1, b1, P1);
    k2<<<dim3(16, 32), 256, 0, stream>>>(P1, w2, b2, p2);
    k3<<<dim3(16, 32), 256, 0, stream>>>(p2, w3, b3, wc, bc, out);
}

// Round 3
// 166.348 us; speedup vs baseline: 1.3638x; 1.3472x over previous
//
#include <hip/hip_runtime.h>

// Problem collapses: output = classifier(node 0) only.
//   out = dot(wc, mean(pool(lrelu(conv3(p2)+b3)))) + bc
//   p2  = pool(lrelu(conv2(12*P1) + 4*b2))      (node 1, indeg=4; sum of
//   P1  = pool(lrelu(conv1(x)+b1))               block1 indegs over {0,2,4,6} = 12)
//
// R3: row-lane restructure. Each lane owns 1 pre-pool row x 4 contiguous
// cols -> one aligned ds_read_b128 per window row (banks tile 0..31,
// conflict-free); column halos via __shfl_up/down(1); vertical pooling via
// __shfl_xor. Grid raised to 1024/1024/512 blocks for 4/4/2 blocks per CU.

#define LRELU(v) fmaxf((v), 0.2f * (v))

// ---------- k1: conv1 4->32 @64x64, +b1, lrelu, pool2, *12 -> P1[b][32][32][32]
__global__ __launch_bounds__(256) void k1(const float* __restrict__ x,
                                          const float* __restrict__ w1,
                                          const float* __restrict__ b1,
                                          float* __restrict__ P1) {
    __shared__ __align__(16) float xs[4][18][68];   // 4 cin x 18 rows x (64+pad)
    const int bx = blockIdx.x;            // 32 = 4 row-blocks x 8 co-groups
    const int b  = blockIdx.y;
    const int rb = bx & 3, cog = bx >> 2;
    const int t  = threadIdx.x;

    // stage rows 16rb-1 .. 16rb+16 (zero outside), 64 cols, 4 cin
    #pragma unroll
    for (int k = 0; k < 5; ++k) {
        int idx = t + k * 256;
        if (idx < 1152) {                  // 4*18*16 float4
            int cin = idx / 288, rem = idx % 288;
            int i = rem >> 4, q4 = rem & 15;
            int gr = 16 * rb - 1 + i;
            float4 v = make_float4(0.f, 0.f, 0.f, 0.f);
            if (gr >= 0 && gr < 64)
                v = *(const float4*)&x[((b * 4 + cin) * 64 + gr) * 64 + 4 * q4];
            *(float4*)&xs[cin][i][4 * q4] = v;
        }
    }
    __syncthreads();

    const int l  = t & 63;
    const int wv = t >> 6;
    const int q  = l & 15, rl = l >> 4;
    const int r  = 4 * wv + rl;            // block-local pre-pool row 0..15

    float acc[4][4];
    #pragma unroll
    for (int g = 0; g < 4; ++g) {
        float bias = b1[cog * 4 + g];
        acc[g][0] = bias; acc[g][1] = bias; acc[g][2] = bias; acc[g][3] = bias;
    }

    #pragma unroll
    for (int c = 0; c < 4; ++c) {
        float win[3][6];
        #pragma unroll
        for (int d = 0; d < 3; ++d) {
            float4 a = *(const float4*)&xs[c][r + d][4 * q];
            float lw = __shfl_up(a.w, 1);   if (q == 0)  lw = 0.f;
            float rw = __shfl_down(a.x, 1); if (q == 15) rw = 0.f;
            win[d][0] = lw;  win[d][1] = a.x; win[d][2] = a.y;
            win[d][3] = a.z; win[d][4] = a.w; win[d][5] = rw;
        }
        #pragma unroll
        for (int g = 0; g < 4; ++g) {
            const float* wp = &w1[((cog * 4 + g) * 4 + c) * 9];
            #pragma unroll
            for (int d = 0; d < 3; ++d)
                #pragma unroll
                for (int j = 0; j < 3; ++j) {
                    float w = wp[3 * d + j];
                    acc[g][0] += w * win[d][j];
                    acc[g][1] += w * win[d][j + 1];
                    acc[g][2] += w * win[d][j + 2];
                    acc[g][3] += w * win[d][j + 3];
                }
        }
    }

    const int prow = 8 * rb + (r >> 1);
    #pragma unroll
    for (int g = 0; g < 4; ++g) {
        float m0 = fmaxf(LRELU(acc[g][0]), LRELU(acc[g][1]));
        float m1 = fmaxf(LRELU(acc[g][2]), LRELU(acc[g][3]));
        float p0 = fmaxf(m0, __shfl_xor(m0, 16));
        float p1 = fmaxf(m1, __shfl_xor(m1, 16));
        if ((rl & 1) == 0) {
            *(float2*)&P1[((b * 32 + cog * 4 + g) * 32 + prow) * 32 + 2 * q] =
                make_float2(12.f * p0, 12.f * p1);
        }
    }
}

// ---------- k2: conv2 32->64 @32x32, +4*b2, lrelu, pool2 -> p2[b][64][16][16]
__global__ __launch_bounds__(256) void k2(const float* __restrict__ P1,
                                          const float* __restrict__ w2,
                                          const float* __restrict__ b2,
                                          float* __restrict__ p2) {
    __shared__ __align__(16) float xs[8][34][36];   // 8-cin chunk x 34 rows x (32+pad)
    const int cog = blockIdx.x;            // 0..31 -> co pair
    const int b   = blockIdx.y;
    const int t   = threadIdx.x;
    const int l   = t & 63, wv = t >> 6;
    const int q   = l & 7, rl = l >> 3;
    const int r   = 8 * wv + rl;           // pre-pool row 0..31

    float acc[2][4];
    #pragma unroll
    for (int g = 0; g < 2; ++g) {
        float bias = 4.f * b2[cog * 2 + g];
        acc[g][0] = bias; acc[g][1] = bias; acc[g][2] = bias; acc[g][3] = bias;
    }

    for (int cc = 0; cc < 4; ++cc) {
        __syncthreads();
        #pragma unroll
        for (int k = 0; k < 8; ++k) {      // 8*32*8 = 2048 float4, exact
            int idx = t + k * 256;
            int cin = idx >> 8, rem = idx & 255;
            int row = rem >> 3, q4 = rem & 7;
            float4 v = *(const float4*)&P1[((b * 32 + cc * 8 + cin) * 32 + row) * 32 + 4 * q4];
            *(float4*)&xs[cin][row + 1][4 * q4] = v;
        }
        if (t < 144) {                     // zero halo rows 0 and 33
            int cin = t / 18, rr = ((t % 18) / 9) ? 33 : 0, q4 = t % 9;
            *(float4*)&xs[cin][rr][4 * q4] = make_float4(0.f, 0.f, 0.f, 0.f);
        }
        __syncthreads();

        #pragma unroll 4
        for (int cl = 0; cl < 8; ++cl) {
            float win[3][6];
            #pragma unroll
            for (int d = 0; d < 3; ++d) {
                float4 a = *(const float4*)&xs[cl][r + d][4 * q];
                float lw = __shfl_up(a.w, 1);   if (q == 0) lw = 0.f;
                float rw = __shfl_down(a.x, 1); if (q == 7) rw = 0.f;
                win[d][0] = lw;  win[d][1] = a.x; win[d][2] = a.y;
                win[d][3] = a.z; win[d][4] = a.w; win[d][5] = rw;
            }
            const int cin = cc * 8 + cl;
            #pragma unroll
            for (int g = 0; g < 2; ++g) {
                const float* wp = &w2[((cog * 2 + g) * 32 + cin) * 9];
                #pragma unroll
                for (int d = 0; d < 3; ++d)
                    #pragma unroll
                    for (int j = 0; j < 3; ++j) {
                        float w = wp[3 * d + j];
                        acc[g][0] += w * win[d][j];
                        acc[g][1] += w * win[d][j + 1];
                        acc[g][2] += w * win[d][j + 2];
                        acc[g][3] += w * win[d][j + 3];
                    }
            }
        }
    }

    const int prow = r >> 1;
    #pragma unroll
    for (int g = 0; g < 2; ++g) {
        float m0 = fmaxf(LRELU(acc[g][0]), LRELU(acc[g][1]));
        float m1 = fmaxf(LRELU(acc[g][2]), LRELU(acc[g][3]));
        float p0 = fmaxf(m0, __shfl_xor(m0, 8));
        float p1 = fmaxf(m1, __shfl_xor(m1, 8));
        if ((rl & 1) == 0) {
            *(float2*)&p2[((b * 64 + cog * 2 + g) * 16 + prow) * 16 + 2 * q] =
                make_float2(p0, p1);
        }
    }
}

// ---------- k3: conv3 64->128 @16x16, +b3, lrelu, pool2, mean, dot wc + bc
__global__ __launch_bounds__(256) void k3(const float* __restrict__ p2,
                                          const float* __restrict__ w3,
                                          const float* __restrict__ b3,
                                          const float* __restrict__ wc,
                                          const float* __restrict__ bc,
                                          float* __restrict__ out) {
    __shared__ __align__(16) float xs[16][18][20];  // 16-cin chunk x 18 rows x (16+pad)
    const int cog = blockIdx.x;            // 0..15 -> 8 co per block (2 per wave)
    const int b   = blockIdx.y;
    const int t   = threadIdx.x;
    const int l   = t & 63;
    const int wv  = __builtin_amdgcn_readfirstlane(t >> 6);
    const int q   = l & 3, rl = l >> 2;
    const int r   = rl;                    // pre-pool row 0..15 (wave = full plane)

    float acc[2][4];
    #pragma unroll
    for (int g = 0; g < 2; ++g) {
        float bias = b3[cog * 8 + wv * 2 + g];
        acc[g][0] = bias; acc[g][1] = bias; acc[g][2] = bias; acc[g][3] = bias;
    }

    for (int cc = 0; cc < 4; ++cc) {
        __syncthreads();
        #pragma unroll
        for (int k = 0; k < 4; ++k) {      // 16*16*4 = 1024 float4, exact
            int idx = t + k * 256;
            int cin = idx >> 6, rem = idx & 63;
            int row = rem >> 2, q4 = rem & 3;
            float4 v = *(const float4*)&p2[((b * 64 + cc * 16 + cin) * 16 + row) * 16 + 4 * q4];
            *(float4*)&xs[cin][row + 1][4 * q4] = v;
        }
        if (t < 160) {                     // zero halo rows 0 and 17
            int cin = t / 10, rr = ((t % 10) / 5) ? 17 : 0, q4 = t % 5;
            *(float4*)&xs[cin][rr][4 * q4] = make_float4(0.f, 0.f, 0.f, 0.f);
        }
        __syncthreads();

        #pragma unroll 4
        for (int cl = 0; cl < 16; ++cl) {
            float win[3][6];
            #pragma unroll
            for (int d = 0; d < 3; ++d) {
                float4 a = *(const float4*)&xs[cl][r + d][4 * q];
                float lw = __shfl_up(a.w, 1);   if (q == 0) lw = 0.f;
                float rw = __shfl_down(a.x, 1); if (q == 3) rw = 0.f;
                win[d][0] = lw;  win[d][1] = a.x; win[d][2] = a.y;
                win[d][3] = a.z; win[d][4] = a.w; win[d][5] = rw;
            }
            const int cin = cc * 16 + cl;
            #pragma unroll
            for (int g = 0; g < 2; ++g) {
                const float* wp = &w3[((cog * 8 + wv * 2 + g) * 64 + cin) * 9];
                #pragma unroll
                for (int d = 0; d < 3; ++d)
                    #pragma unroll
                    for (int j = 0; j < 3; ++j) {
                        float w = wp[3 * d + j];
                        acc[g][0] += w * win[d][j];
                        acc[g][1] += w * win[d][j + 1];
                        acc[g][2] += w * win[d][j + 2];
                        acc[g][3] += w * win[d][j + 3];
                    }
            }
        }
    }

    float v = 0.f;
    #pragma unroll
    for (int g = 0; g < 2; ++g) {
        float m0 = fmaxf(LRELU(acc[g][0]), LRELU(acc[g][1]));
        float m1 = fmaxf(LRELU(acc[g][2]), LRELU(acc[g][3]));
        float p0 = fmaxf(m0, __shfl_xor(m0, 4));
        float p1 = fmaxf(m1, __shfl_xor(m1, 4));
        if ((rl & 1) == 0) v += (p0 + p1) * wc[cog * 8 + wv * 2 + g];
    }
    #pragma unroll
    for (int off = 32; off > 0; off >>= 1) v += __shfl_xor(v, off);
    if (l == 0) {
        float p = v * (1.f / 64.f);
        if (cog == 0 && wv == 0) p += bc[0];
        atomicAdd(&out[b], p);
    }
}

extern "C" void kernel_launch(void* const* d_in, const int* in_sizes, int n_in,
                              void* d_out, int out_size, void* d_ws, size_t ws_size,
                              hipStream_t stream) {
    const float* x  = (const float*)d_in[0];
    const float* w1 = (const float*)d_in[1];
    const float* b1 = (const float*)d_in[2];
    const float* w2 = (const float*)d_in[3];
    const float* b2 = (const float*)d_in[4];
    const float* w3 = (const float*)d_in[5];
    const float* b3 = (const float*)d_in[6];
    const float* wc = (const float*)d_in[7];
    const float* bc = (const float*)d_in[8];
    float* out = (float*)d_out;

    float* P1 = (float*)d_ws;                    // [32,32,32,32] = 4 MB
    float* p2 = P1 + 32 * 32 * 32 * 32;          // [32,64,16,16] = 512 KB

    hipMemsetAsync(out, 0, 32 * sizeof(float), stream);
    k1<<<dim3(32, 32), 256, 0, stream>>>(x, w1, b1, P1);
    k2<<<dim3(32, 32), 256, 0, stream>>>(P1, w2, b2, p2);
    k3<<<dim3(16, 32), 256, 0, stream>>>(p2, w3, b3, wc, bc, out);
}